// Round 1
// baseline (515.897 us; speedup 1.0000x reference)
//
#include <hip/hip_runtime.h>
#include <math.h>

#define BB 16
#define TOPK 2000
#define KEEPK 750
#define CAND_CAP 4096
#define EDGE_CAP 8192
#define HIST_BINS 256
#define BIN_BASE 0x3E99u   // (bits of 0.3f) >> 16

// ---------------- ws layout ----------------
#define OFF_HIST   0                       // 16*256*4 = 16384
#define OFF_CCOUNT 16384                   // 64
#define OFF_ECOUNT 16448                   // 64
#define ZERO_BYTES 16512
#define OFF_TBITS  16512                   // 64
#define OFF_SBITS  16576                   // B*N*4
// rest computed at launch

// ---------------- kernel 1: scores + histogram ----------------
__global__ void k_scores(const float* __restrict__ conf, const float* __restrict__ iou,
                         unsigned* __restrict__ sbits, unsigned* __restrict__ hist, int N) {
  __shared__ unsigned h[HIST_BINS];
  int b = blockIdx.y;
  for (int i = threadIdx.x; i < HIST_BINS; i += blockDim.x) h[i] = 0;
  __syncthreads();
  const float2* c2 = (const float2*)conf + (size_t)b * N;
  const float* iu = iou + (size_t)b * N;
  unsigned* sb = sbits + (size_t)b * N;
  int n0 = blockIdx.x * (blockDim.x * 8);
  for (int k = 0; k < 8; ++k) {
    int n = n0 + k * blockDim.x + threadIdx.x;
    if (n < N) {
      float2 c = c2[n];
      float m = fmaxf(c.x, c.y);
      // correctly-rounded f32 exp via double to best match the reference softmax
      float e0 = (float)exp((double)(c.x - m));
      float e1 = (float)exp((double)(c.y - m));
      float p1 = e1 / (e0 + e1);
      float ic = fminf(fmaxf(iu[n], 0.0f), 1.0f);
      float s = sqrtf(p1 * ic);
      s = (s >= 0.3f) ? s : 0.0f;
      unsigned bits = __float_as_uint(s);
      sb[n] = bits;
      if (bits != 0u) {
        int bin = (int)(bits >> 16) - (int)BIN_BASE;
        bin = bin < 0 ? 0 : (bin > 255 ? 255 : bin);
        atomicAdd(&h[bin], 1u);
      }
    }
  }
  __syncthreads();
  for (int i = threadIdx.x; i < HIST_BINS; i += blockDim.x)
    if (h[i]) atomicAdd(&hist[b * HIST_BINS + i], h[i]);
}

// ---------------- kernel 2: per-batch bin threshold (1 block, wave per batch) ----------------
__global__ __launch_bounds__(1024) void k_thresh(const unsigned* __restrict__ hist,
                                                 unsigned* __restrict__ tbits) {
  int wv = threadIdx.x >> 6, lane = threadIdx.x & 63;
  if (wv >= BB) return;
  const unsigned* h = hist + wv * HIST_BINS;
  // lane l covers descending bins 255-4l-k, k=0..3
  unsigned v0 = h[255 - (4 * lane + 0)];
  unsigned v1 = h[255 - (4 * lane + 1)];
  unsigned v2 = h[255 - (4 * lane + 2)];
  unsigned v3 = h[255 - (4 * lane + 3)];
  unsigned p0 = v0, p1 = p0 + v1, p2 = p1 + v2, p3 = p2 + v3;
  unsigned tot = p3, pre = tot;
  for (int off = 1; off < 64; off <<= 1) {
    unsigned q = __shfl_up(pre, off);
    if (lane >= off) pre += q;
  }
  unsigned excl = pre - tot;
  int kk = -1;
  if (excl + p0 >= TOPK) kk = 0;
  else if (excl + p1 >= TOPK) kk = 1;
  else if (excl + p2 >= TOPK) kk = 2;
  else if (excl + p3 >= TOPK) kk = 3;
  unsigned long long m = __ballot(kk >= 0);
  int bin = 0;
  if (m != 0ull) {
    int fl = __ffsll((unsigned long long)m) - 1;
    int fk = __shfl(kk, fl);
    bin = 255 - (4 * fl + fk);
  }
  if (lane == 0) tbits[wv] = ((unsigned)(BIN_BASE + (unsigned)bin)) << 16;
}

// ---------------- kernel 3: compact candidates ----------------
__global__ void k_compact(const unsigned* __restrict__ sbits, const unsigned* __restrict__ tbits,
                          unsigned* __restrict__ ccount, unsigned long long* __restrict__ ckeys,
                          int N) {
  int b = blockIdx.y;
  unsigned T = tbits[b];
  const unsigned* sb = sbits + (size_t)b * N;
  int lane = threadIdx.x & 63;
  int n0 = blockIdx.x * (blockDim.x * 8);
  for (int k = 0; k < 8; ++k) {
    int n = n0 + k * blockDim.x + threadIdx.x;
    bool p = (n < N) && (sb[n] >= T);
    unsigned long long mask = __ballot(p);
    if (mask != 0ull) {
      int leader = __ffsll((unsigned long long)mask) - 1;
      unsigned base = 0;
      if (lane == leader) base = atomicAdd(&ccount[b], (unsigned)__popcll(mask));
      base = __shfl(base, leader);
      if (p) {
        unsigned pos = base + (unsigned)__popcll(mask & ((1ull << lane) - 1ull));
        if (pos < CAND_CAP)
          ckeys[(size_t)b * CAND_CAP + pos] =
              ((unsigned long long)sb[n] << 32) | (unsigned)(~(unsigned)n);
      }
    }
  }
}

// ---------------- kernel 4: per-batch bitonic sort (desc) + emit top arrays ----------------
__global__ __launch_bounds__(1024) void k_sort(const unsigned* __restrict__ ccount,
                                               const unsigned long long* __restrict__ ckeys,
                                               float* __restrict__ top_s,
                                               unsigned* __restrict__ top_i) {
  __shared__ unsigned long long s[CAND_CAP];
  int b = blockIdx.x;
  unsigned c = ccount[b];
  if (c > CAND_CAP) c = CAND_CAP;
  for (int i = threadIdx.x; i < CAND_CAP; i += 1024)
    s[i] = (i < (int)c) ? ckeys[(size_t)b * CAND_CAP + i] : 0ull;
  __syncthreads();
  for (int k = 2; k <= CAND_CAP; k <<= 1) {
    for (int j = k >> 1; j > 0; j >>= 1) {
      for (int i = threadIdx.x; i < CAND_CAP; i += 1024) {
        int p = i ^ j;
        if (p > i) {
          bool up = (i & k) == 0;  // flipped comparator -> overall descending
          unsigned long long a = s[i], bb2 = s[p];
          bool sw = up ? (a < bb2) : (a > bb2);
          if (sw) { s[i] = bb2; s[p] = a; }
        }
      }
      __syncthreads();
    }
  }
  for (int r = threadIdx.x; r < TOPK; r += 1024) {
    unsigned long long key = s[r];
    top_s[b * TOPK + r] = __uint_as_float((unsigned)(key >> 32));
    top_i[b * TOPK + r] = ~(unsigned)key;
  }
}

// ---------------- kernel 5: gather+decode selected boxes ----------------
__global__ void k_decode(const float* __restrict__ loc, const unsigned* __restrict__ top_i,
                         float* __restrict__ out, float4* __restrict__ boxes4, int N) {
  int r = blockIdx.x * blockDim.x + threadIdx.x;
  int b = blockIdx.y;
  if (r >= TOPK) return;
  unsigned idxu = top_i[b * TOPK + r];
  if (idxu >= (unsigned)N) idxu = 0;  // pad safety (never hit for this input)
  int i = (int)idxu;
  int off, fw, st, nm, lvl;
  if (i < 97200)       { lvl = 0; off = 0;      fw = 240; st = 8;  nm = 3; }
  else if (i < 113520) { lvl = 1; off = 97200;  fw = 120; st = 16; nm = 2; }
  else if (i < 117600) { lvl = 2; off = 113520; fw = 60;  st = 32; nm = 2; }
  else                 { lvl = 3; off = 117600; fw = 30;  st = 64; nm = 3; }
  int t = i - off;
  int cell = t / nm;
  int k = t - cell * nm;
  int row = cell / fw;
  int col = cell - row * fw;
  int msv = (lvl == 0) ? (k == 0 ? 10 : (k == 1 ? 16 : 24))
          : (lvl == 1) ? (k == 0 ? 32 : 48)
          : (lvl == 2) ? (k == 0 ? 64 : 96)
                       : (k == 0 ? 128 : (k == 1 ? 192 : 256));
  // priors built in f64 then cast to f32 (matches numpy)
  float cx  = (float)(((double)col + 0.5) * (double)st / 1920.0);
  float cy  = (float)(((double)row + 0.5) * (double)st / 1080.0);
  float skx = (float)((double)msv / 1920.0);
  float sky = (float)((double)msv / 1080.0);
  const float2* lp2 = (const float2*)(loc + ((size_t)b * N + (size_t)i) * 14);
  float l[14];
#pragma unroll
  for (int q = 0; q < 7; ++q) { float2 v = lp2[q]; l[2 * q] = v.x; l[2 * q + 1] = v.y; }
  float cx2 = cx + (l[0] * 0.1f) * skx;
  float cy2 = cy + (l[1] * 0.1f) * sky;
  float wx = skx * expf(l[2] * 0.1f);
  float wy = sky * expf(l[3] * 0.2f);
  float x1 = cx2 - wx * 0.5f, y1 = cy2 - wy * 0.5f;
  float x2 = x1 + wx, y2 = y1 + wy;
  float X1 = x1 * 1920.0f, Y1 = y1 * 1080.0f, X2 = x2 * 1920.0f, Y2 = y2 * 1080.0f;
  float* o = out + ((size_t)b * TOPK + r) * 15;
  o[0] = X1; o[1] = Y1; o[2] = X2; o[3] = Y2;
#pragma unroll
  for (int q = 0; q < 5; ++q) {
    o[4 + 2 * q] = (cx + (l[4 + 2 * q] * 0.1f) * skx) * 1920.0f;
    o[5 + 2 * q] = (cy + (l[5 + 2 * q] * 0.1f) * sky) * 1080.0f;
  }
  boxes4[b * TOPK + r] = make_float4(X1, Y1, X2, Y2);
}

// ---------------- kernel 6: sparse overlap edges (j<i, iou>0.3) ----------------
__global__ __launch_bounds__(64) void k_edges(const float4* __restrict__ boxes4,
                                              unsigned* __restrict__ ecount,
                                              unsigned* __restrict__ edges) {
  int b = blockIdx.z;
  int ib = blockIdx.x, jb = blockIdx.y;
  if (jb > ib) return;
  __shared__ float4 cb[64];
  int j0 = jb * 64;
  {
    int j = j0 + threadIdx.x;
    cb[threadIdx.x] = (j < TOPK) ? boxes4[b * TOPK + j] : make_float4(0, 0, 0, 0);
  }
  __syncthreads();
  int r = ib * 64 + threadIdx.x;
  if (r >= TOPK) return;
  float4 A = boxes4[b * TOPK + r];
  float areaA = fmaxf(A.z - A.x, 0.f) * fmaxf(A.w - A.y, 0.f);
  for (int c = 0; c < 64; ++c) {
    int j = j0 + c;
    if (j >= r) break;
    float4 Bx = cb[c];
    float xx1 = fmaxf(A.x, Bx.x), yy1 = fmaxf(A.y, Bx.y);
    float xx2 = fminf(A.z, Bx.z), yy2 = fminf(A.w, Bx.w);
    float w = fmaxf(xx2 - xx1, 0.f), hgt = fmaxf(yy2 - yy1, 0.f);
    float inter = w * hgt;
    float areaB = fmaxf(Bx.z - Bx.x, 0.f) * fmaxf(Bx.w - Bx.y, 0.f);
    float iouv = inter / (areaA + areaB - inter + 1e-9f);
    if (iouv > 0.3f) {
      unsigned pos = atomicAdd(&ecount[b], 1u);
      if (pos < EDGE_CAP) edges[b * EDGE_CAP + pos] = ((unsigned)r << 16) | (unsigned)j;
    }
  }
}

// ---------------- kernel 7: greedy NMS via Jacobi on sparse edges + cumsum<=750 ----------------
__global__ __launch_bounds__(256) void k_nms(const float* __restrict__ top_s,
                                             const unsigned* __restrict__ ecount,
                                             const unsigned* __restrict__ edges,
                                             float* __restrict__ out) {
  int b = blockIdx.x;
  __shared__ unsigned long long A[32], K[32], S[32];
  __shared__ unsigned pref[32];
  int tid = threadIdx.x, lane = tid & 63, wv = tid >> 6;
  for (int base = 0; base < 2048; base += 256) {
    int i = base + tid;
    bool act = (i < TOPK) && (top_s[b * TOPK + i] > 0.0f);
    unsigned long long m = __ballot(act);
    if (lane == 0) { int w = (base >> 6) + wv; A[w] = m; K[w] = m; }
  }
  __syncthreads();
  unsigned E = ecount[b];
  if (E > EDGE_CAP) E = EDGE_CAP;
  for (int it = 0; it < 24; ++it) {
    if (tid < 32) S[tid] = 0ull;
    __syncthreads();
    for (unsigned e = tid; e < E; e += 256) {
      unsigned v = edges[b * EDGE_CAP + e];
      unsigned i = v >> 16, j = v & 0xFFFFu;
      if ((K[j >> 6] >> (j & 63)) & 1ull)
        atomicOr(&S[i >> 6], 1ull << (i & 63));
    }
    __syncthreads();
    if (tid < 32) K[tid] = A[tid] & ~S[tid];
    __syncthreads();
  }
  if (tid == 0) {
    unsigned acc = 0;
    for (int w = 0; w < 32; ++w) { pref[w] = acc; acc += (unsigned)__popcll(K[w]); }
  }
  __syncthreads();
  for (int base = 0; base < 2048; base += 256) {
    int i = base + tid;
    if (i < TOPK) {
      int w = i >> 6;
      unsigned long long bit = (K[w] >> (i & 63)) & 1ull;
      unsigned rank = pref[w] + (unsigned)__popcll(K[w] & ((1ull << (i & 63)) - 1ull)) + (unsigned)bit;
      float sv = top_s[b * TOPK + i];
      out[((size_t)b * TOPK + i) * 15 + 14] = (bit && rank <= KEEPK) ? sv : 0.0f;
    }
  }
}

extern "C" void kernel_launch(void* const* d_in, const int* in_sizes, int n_in,
                              void* d_out, int out_size, void* d_ws, size_t ws_size,
                              hipStream_t stream) {
  const float* loc  = (const float*)d_in[0];
  const float* conf = (const float*)d_in[1];
  const float* iou  = (const float*)d_in[2];
  float* out = (float*)d_out;
  int N = in_sizes[2] / BB;  // iou is [B,N,1]

  char* ws = (char*)d_ws;
  unsigned* hist   = (unsigned*)(ws + OFF_HIST);
  unsigned* ccount = (unsigned*)(ws + OFF_CCOUNT);
  unsigned* ecount = (unsigned*)(ws + OFF_ECOUNT);
  unsigned* tbits  = (unsigned*)(ws + OFF_TBITS);
  unsigned* sbits  = (unsigned*)(ws + OFF_SBITS);
  size_t off = (size_t)OFF_SBITS + (size_t)BB * N * 4;
  off = (off + 15) & ~(size_t)15;
  unsigned long long* ckeys = (unsigned long long*)(ws + off); off += (size_t)BB * CAND_CAP * 8;
  float*    top_s = (float*)(ws + off);    off += (size_t)BB * TOPK * 4;
  unsigned* top_i = (unsigned*)(ws + off); off += (size_t)BB * TOPK * 4;
  off = (off + 15) & ~(size_t)15;
  float4* boxes4 = (float4*)(ws + off);    off += (size_t)BB * TOPK * 16;
  unsigned* edges = (unsigned*)(ws + off); off += (size_t)BB * EDGE_CAP * 4;

  hipMemsetAsync(ws, 0, ZERO_BYTES, stream);

  dim3 gscan((N + 2047) / 2048, BB);
  k_scores<<<gscan, 256, 0, stream>>>(conf, iou, sbits, hist, N);
  k_thresh<<<1, 1024, 0, stream>>>(hist, tbits);
  k_compact<<<gscan, 256, 0, stream>>>(sbits, tbits, ccount, ckeys, N);
  k_sort<<<BB, 1024, 0, stream>>>(ccount, ckeys, top_s, top_i);
  k_decode<<<dim3((TOPK + 255) / 256, BB), 256, 0, stream>>>(loc, top_i, out, boxes4, N);
  k_edges<<<dim3(32, 32, BB), 64, 0, stream>>>(boxes4, ecount, edges);
  k_nms<<<BB, 256, 0, stream>>>(top_s, ecount, edges, out);
}

// Round 2
// 296.834 us; speedup vs baseline: 1.7380x; 1.7380x over previous
//
#include <hip/hip_runtime.h>
#include <math.h>

#define BB 16
#define TOPK 2000
#define KEEPK 750
#define CAND_CAP 4096
#define EDGE_CAP 8192
#define HIST_BINS 256
#define BIN_BASE 0x3E99u   // (bits of 0.3f) >> 16

// ---------------- ws layout ----------------
#define OFF_HIST   0                       // 16*256*4 = 16384
#define OFF_CCOUNT 16384                   // 64
#define OFF_ECOUNT 16448                   // 64
#define ZERO_BYTES 16512
#define OFF_SBITS  16512                   // B*N*4

// ---------------- kernel 1: scores + histogram (16 elems/thread) ----------------
__global__ __launch_bounds__(256) void k_scores(const float* __restrict__ conf,
                                                const float* __restrict__ iou,
                                                unsigned* __restrict__ sbits,
                                                unsigned* __restrict__ hist, int N) {
  __shared__ unsigned h[HIST_BINS];
  int b = blockIdx.y;
  for (int i = threadIdx.x; i < HIST_BINS; i += blockDim.x) h[i] = 0;
  __syncthreads();
  const float2* c2 = (const float2*)conf + (size_t)b * N;
  const float* iu = iou + (size_t)b * N;
  unsigned* sb = sbits + (size_t)b * N;
  int n0 = blockIdx.x * 4096;
#pragma unroll 4
  for (int k = 0; k < 16; ++k) {
    int n = n0 + k * 256 + threadIdx.x;
    if (n < N) {
      float2 c = c2[n];
      float m = fmaxf(c.x, c.y);
      // correctly-rounded f32 exp via double to match the reference softmax
      float e0 = (float)exp((double)(c.x - m));
      float e1 = (float)exp((double)(c.y - m));
      float p1 = e1 / (e0 + e1);
      float ic = fminf(fmaxf(iu[n], 0.0f), 1.0f);
      float s = sqrtf(p1 * ic);
      s = (s >= 0.3f) ? s : 0.0f;
      unsigned bits = __float_as_uint(s);
      sb[n] = bits;
      if (bits != 0u) {
        int bin = (int)(bits >> 16) - (int)BIN_BASE;
        bin = bin < 0 ? 0 : (bin > 255 ? 255 : bin);
        atomicAdd(&h[bin], 1u);
      }
    }
  }
  __syncthreads();
  for (int i = threadIdx.x; i < HIST_BINS; i += blockDim.x)
    if (h[i]) atomicAdd(&hist[b * HIST_BINS + i], h[i]);
}

// ---------------- kernel 2: fused threshold + compact (1 atomic per block) -------
__global__ __launch_bounds__(256) void k_compact(const unsigned* __restrict__ sbits,
                                                 const unsigned* __restrict__ hist,
                                                 unsigned* __restrict__ ccount,
                                                 unsigned long long* __restrict__ ckeys,
                                                 int N) {
  __shared__ unsigned sT;
  __shared__ unsigned long long masks[32];   // [iter*4 + wave]
  __shared__ unsigned wioff[32];
  __shared__ unsigned blockbase;
  int b = blockIdx.y;
  int tid = threadIdx.x, lane = tid & 63, wv = tid >> 6;

  // ---- wave 0: recompute per-batch bin threshold from histogram ----
  if (tid < 64) {
    const unsigned* h = hist + b * HIST_BINS;
    unsigned v0 = h[255 - (4 * lane + 0)];
    unsigned v1 = h[255 - (4 * lane + 1)];
    unsigned v2 = h[255 - (4 * lane + 2)];
    unsigned v3 = h[255 - (4 * lane + 3)];
    unsigned p0 = v0, p1 = p0 + v1, p2 = p1 + v2, p3 = p2 + v3;
    unsigned tot = p3, pre = tot;
    for (int off = 1; off < 64; off <<= 1) {
      unsigned q = __shfl_up(pre, off);
      if (lane >= off) pre += q;
    }
    unsigned excl = pre - tot;
    int kk = -1;
    if (excl + p0 >= TOPK) kk = 0;
    else if (excl + p1 >= TOPK) kk = 1;
    else if (excl + p2 >= TOPK) kk = 2;
    else if (excl + p3 >= TOPK) kk = 3;
    unsigned long long m = __ballot(kk >= 0);
    int bin = 0;
    if (m != 0ull) {
      int fl = __ffsll((unsigned long long)m) - 1;
      int fk = __shfl(kk, fl);
      bin = 255 - (4 * fl + fk);
    }
    if (lane == 0) sT = ((unsigned)(BIN_BASE + (unsigned)bin)) << 16;
  }
  __syncthreads();
  unsigned T = sT;

  const unsigned* sb = sbits + (size_t)b * N;
  int n0 = blockIdx.x * 2048;
  unsigned v[8];
  unsigned long long mk[8];
#pragma unroll
  for (int k = 0; k < 8; ++k) {
    int n = n0 + k * 256 + tid;
    v[k] = (n < N) ? sb[n] : 0u;
    bool p = v[k] >= T;              // T >= 0x3E990000 > 0, so zero scores fail
    mk[k] = __ballot(p);
    if (lane == 0) masks[k * 4 + wv] = mk[k];
  }
  __syncthreads();
  if (tid < 64) {
    unsigned c = (tid < 32) ? (unsigned)__popcll(masks[tid]) : 0u;
    unsigned pre = c;
    for (int off = 1; off < 64; off <<= 1) {
      unsigned q = __shfl_up(pre, off);
      if (lane >= off) pre += q;
    }
    if (tid < 32) wioff[tid] = pre - c;          // exclusive prefix
    if (tid == 31) blockbase = atomicAdd(&ccount[b], pre);  // pre@31 = block total
  }
  __syncthreads();
  unsigned base = blockbase;
#pragma unroll
  for (int k = 0; k < 8; ++k) {
    if ((mk[k] >> lane) & 1ull) {
      unsigned pos = base + wioff[k * 4 + wv] +
                     (unsigned)__popcll(mk[k] & ((1ull << lane) - 1ull));
      if (pos < CAND_CAP) {
        int n = n0 + k * 256 + tid;
        ckeys[(size_t)b * CAND_CAP + pos] =
            ((unsigned long long)v[k] << 32) | (unsigned)(~(unsigned)n);
      }
    }
  }
}

// ---------------- kernel 3: per-batch bitonic sort (desc) ----------------
__global__ __launch_bounds__(1024) void k_sort(const unsigned* __restrict__ ccount,
                                               const unsigned long long* __restrict__ ckeys,
                                               float* __restrict__ top_s,
                                               unsigned* __restrict__ top_i) {
  __shared__ unsigned long long s[CAND_CAP];
  int b = blockIdx.x;
  unsigned c = ccount[b];
  if (c > CAND_CAP) c = CAND_CAP;
  for (int i = threadIdx.x; i < CAND_CAP; i += 1024)
    s[i] = (i < (int)c) ? ckeys[(size_t)b * CAND_CAP + i] : 0ull;
  __syncthreads();
  for (int k = 2; k <= CAND_CAP; k <<= 1) {
    for (int j = k >> 1; j > 0; j >>= 1) {
      for (int i = threadIdx.x; i < CAND_CAP; i += 1024) {
        int p = i ^ j;
        if (p > i) {
          bool up = (i & k) == 0;  // flipped comparator -> overall descending
          unsigned long long a = s[i], bb2 = s[p];
          bool sw = up ? (a < bb2) : (a > bb2);
          if (sw) { s[i] = bb2; s[p] = a; }
        }
      }
      __syncthreads();
    }
  }
  for (int r = threadIdx.x; r < TOPK; r += 1024) {
    unsigned long long key = s[r];
    top_s[b * TOPK + r] = __uint_as_float((unsigned)(key >> 32));
    top_i[b * TOPK + r] = ~(unsigned)key;
  }
}

// ---------------- kernel 4: gather+decode selected boxes ----------------
__global__ __launch_bounds__(256) void k_decode(const float* __restrict__ loc,
                                                const unsigned* __restrict__ top_i,
                                                float* __restrict__ out,
                                                float4* __restrict__ boxes4, int N) {
  int r = blockIdx.x * blockDim.x + threadIdx.x;
  int b = blockIdx.y;
  if (r >= TOPK) return;
  unsigned idxu = top_i[b * TOPK + r];
  if (idxu >= (unsigned)N) idxu = 0;  // pad safety
  int i = (int)idxu;
  int off, fw, st, nm, lvl;
  if (i < 97200)       { lvl = 0; off = 0;      fw = 240; st = 8;  nm = 3; }
  else if (i < 113520) { lvl = 1; off = 97200;  fw = 120; st = 16; nm = 2; }
  else if (i < 117600) { lvl = 2; off = 113520; fw = 60;  st = 32; nm = 2; }
  else                 { lvl = 3; off = 117600; fw = 30;  st = 64; nm = 3; }
  int t = i - off;
  int cell = t / nm;
  int k = t - cell * nm;
  int row = cell / fw;
  int col = cell - row * fw;
  int msv = (lvl == 0) ? (k == 0 ? 10 : (k == 1 ? 16 : 24))
          : (lvl == 1) ? (k == 0 ? 32 : 48)
          : (lvl == 2) ? (k == 0 ? 64 : 96)
                       : (k == 0 ? 128 : (k == 1 ? 192 : 256));
  float cx  = (float)(((double)col + 0.5) * (double)st / 1920.0);
  float cy  = (float)(((double)row + 0.5) * (double)st / 1080.0);
  float skx = (float)((double)msv / 1920.0);
  float sky = (float)((double)msv / 1080.0);
  const float2* lp2 = (const float2*)(loc + ((size_t)b * N + (size_t)i) * 14);
  float l[14];
#pragma unroll
  for (int q = 0; q < 7; ++q) { float2 v = lp2[q]; l[2 * q] = v.x; l[2 * q + 1] = v.y; }
  float cx2 = cx + (l[0] * 0.1f) * skx;
  float cy2 = cy + (l[1] * 0.1f) * sky;
  float wx = skx * expf(l[2] * 0.1f);
  float wy = sky * expf(l[3] * 0.2f);
  float x1 = cx2 - wx * 0.5f, y1 = cy2 - wy * 0.5f;
  float x2 = x1 + wx, y2 = y1 + wy;
  float X1 = x1 * 1920.0f, Y1 = y1 * 1080.0f, X2 = x2 * 1920.0f, Y2 = y2 * 1080.0f;
  float* o = out + ((size_t)b * TOPK + r) * 15;
  o[0] = X1; o[1] = Y1; o[2] = X2; o[3] = Y2;
#pragma unroll
  for (int q = 0; q < 5; ++q) {
    o[4 + 2 * q] = (cx + (l[4 + 2 * q] * 0.1f) * skx) * 1920.0f;
    o[5 + 2 * q] = (cy + (l[5 + 2 * q] * 0.1f) * sky) * 1080.0f;
  }
  boxes4[b * TOPK + r] = make_float4(X1, Y1, X2, Y2);
}

// ---- kernel 5: sparse overlap edges, 256x256 triangular tiles, 1 atomic/block ----
__global__ __launch_bounds__(256) void k_edges(const float4* __restrict__ boxes4,
                                               unsigned* __restrict__ ecount,
                                               unsigned* __restrict__ edges) {
  __shared__ float4 cb[256];
  __shared__ unsigned loc_e[1024];
  __shared__ unsigned lcnt, gbase;
  int b = blockIdx.y;
  int t = blockIdx.x;                 // 0..35 triangular tile id
  int ib = 0;
  while ((ib + 1) * (ib + 2) / 2 <= t) ++ib;
  int jb = t - ib * (ib + 1) / 2;
  int tid = threadIdx.x;
  if (tid == 0) lcnt = 0;
  int j0 = jb * 256;
  {
    int j = j0 + tid;
    cb[tid] = (j < TOPK) ? boxes4[b * TOPK + j]
                         : make_float4(-1e30f, -1e30f, -1e30f, -1e30f);
  }
  __syncthreads();
  int r = ib * 256 + tid;
  bool valid = r < TOPK;
  float4 A = valid ? boxes4[b * TOPK + r] : make_float4(0, 0, 0, 0);
  float areaA = fmaxf(A.z - A.x, 0.f) * fmaxf(A.w - A.y, 0.f);
  int cmax = r - j0;
  if (cmax > 256) cmax = 256;
  if (!valid) cmax = 0;
  for (int c = 0; c < cmax; ++c) {
    float4 Bx = cb[c];
    float xx1 = fmaxf(A.x, Bx.x), yy1 = fmaxf(A.y, Bx.y);
    float xx2 = fminf(A.z, Bx.z), yy2 = fminf(A.w, Bx.w);
    float w = fmaxf(xx2 - xx1, 0.f), hgt = fmaxf(yy2 - yy1, 0.f);
    float inter = w * hgt;
    float areaB = fmaxf(Bx.z - Bx.x, 0.f) * fmaxf(Bx.w - Bx.y, 0.f);
    float iouv = inter / (areaA + areaB - inter + 1e-9f);
    if (iouv > 0.3f) {
      unsigned p = atomicAdd(&lcnt, 1u);
      if (p < 1024u) loc_e[p] = ((unsigned)r << 16) | (unsigned)(j0 + c);
    }
  }
  __syncthreads();
  unsigned cnt = lcnt;
  if (cnt > 1024u) cnt = 1024u;
  if (tid == 0 && cnt) gbase = atomicAdd(&ecount[b], cnt);
  __syncthreads();
  if (cnt)
    for (unsigned e = tid; e < cnt; e += 256) {
      unsigned p = gbase + e;
      if (p < EDGE_CAP) edges[b * EDGE_CAP + p] = loc_e[e];
    }
}

// ---- kernel 6: greedy NMS (Jacobi fixpoint, LDS edge cache, early exit) ----
__global__ __launch_bounds__(256) void k_nms(const float* __restrict__ top_s,
                                             const unsigned* __restrict__ ecount,
                                             const unsigned* __restrict__ edges,
                                             float* __restrict__ out) {
  int b = blockIdx.x;
  __shared__ unsigned long long A[32], K[32], S[32];
  __shared__ unsigned pref[32];
  __shared__ unsigned ecache[2048];
  __shared__ int changed;
  int tid = threadIdx.x, lane = tid & 63, wv = tid >> 6;
  for (int base = 0; base < 2048; base += 256) {
    int i = base + tid;
    bool act = (i < TOPK) && (top_s[b * TOPK + i] > 0.0f);
    unsigned long long m = __ballot(act);
    if (lane == 0) { int w = (base >> 6) + wv; A[w] = m; K[w] = m; }
  }
  unsigned E = ecount[b];
  if (E > EDGE_CAP) E = EDGE_CAP;
  unsigned Ec = E > 2048u ? 2048u : E;
  for (unsigned e = tid; e < Ec; e += 256) ecache[e] = edges[b * EDGE_CAP + e];
  __syncthreads();
  for (int it = 0; it < 32; ++it) {
    if (tid == 0) changed = 0;
    if (tid < 32) S[tid] = 0ull;
    __syncthreads();
    for (unsigned e = tid; e < Ec; e += 256) {
      unsigned v = ecache[e];
      unsigned i = v >> 16, j = v & 0xFFFFu;
      if ((K[j >> 6] >> (j & 63)) & 1ull) atomicOr(&S[i >> 6], 1ull << (i & 63));
    }
    for (unsigned e = 2048u + tid; e < E; e += 256) {
      unsigned v = edges[b * EDGE_CAP + e];
      unsigned i = v >> 16, j = v & 0xFFFFu;
      if ((K[j >> 6] >> (j & 63)) & 1ull) atomicOr(&S[i >> 6], 1ull << (i & 63));
    }
    __syncthreads();
    if (tid < 32) {
      unsigned long long nk = A[tid] & ~S[tid];
      if (nk != K[tid]) { K[tid] = nk; changed = 1; }
    }
    __syncthreads();
    if (!changed) break;
  }
  if (tid == 0) {
    unsigned acc = 0;
    for (int w = 0; w < 32; ++w) { pref[w] = acc; acc += (unsigned)__popcll(K[w]); }
  }
  __syncthreads();
  for (int base = 0; base < 2048; base += 256) {
    int i = base + tid;
    if (i < TOPK) {
      int w = i >> 6;
      unsigned long long bit = (K[w] >> (i & 63)) & 1ull;
      unsigned rank = pref[w] + (unsigned)__popcll(K[w] & ((1ull << (i & 63)) - 1ull)) +
                      (unsigned)bit;
      float sv = top_s[b * TOPK + i];
      out[((size_t)b * TOPK + i) * 15 + 14] = (bit && rank <= KEEPK) ? sv : 0.0f;
    }
  }
}

extern "C" void kernel_launch(void* const* d_in, const int* in_sizes, int n_in,
                              void* d_out, int out_size, void* d_ws, size_t ws_size,
                              hipStream_t stream) {
  const float* loc  = (const float*)d_in[0];
  const float* conf = (const float*)d_in[1];
  const float* iou  = (const float*)d_in[2];
  float* out = (float*)d_out;
  int N = in_sizes[2] / BB;  // iou is [B,N,1]

  char* ws = (char*)d_ws;
  unsigned* hist   = (unsigned*)(ws + OFF_HIST);
  unsigned* ccount = (unsigned*)(ws + OFF_CCOUNT);
  unsigned* ecount = (unsigned*)(ws + OFF_ECOUNT);
  unsigned* sbits  = (unsigned*)(ws + OFF_SBITS);
  size_t off = (size_t)OFF_SBITS + (size_t)BB * N * 4;
  off = (off + 15) & ~(size_t)15;
  unsigned long long* ckeys = (unsigned long long*)(ws + off); off += (size_t)BB * CAND_CAP * 8;
  float*    top_s = (float*)(ws + off);    off += (size_t)BB * TOPK * 4;
  unsigned* top_i = (unsigned*)(ws + off); off += (size_t)BB * TOPK * 4;
  off = (off + 15) & ~(size_t)15;
  float4* boxes4 = (float4*)(ws + off);    off += (size_t)BB * TOPK * 16;
  unsigned* edges = (unsigned*)(ws + off); off += (size_t)BB * EDGE_CAP * 4;

  hipMemsetAsync(ws, 0, ZERO_BYTES, stream);

  k_scores<<<dim3((N + 4095) / 4096, BB), 256, 0, stream>>>(conf, iou, sbits, hist, N);
  k_compact<<<dim3((N + 2047) / 2048, BB), 256, 0, stream>>>(sbits, hist, ccount, ckeys, N);
  k_sort<<<BB, 1024, 0, stream>>>(ccount, ckeys, top_s, top_i);
  k_decode<<<dim3((TOPK + 255) / 256, BB), 256, 0, stream>>>(loc, top_i, out, boxes4, N);
  k_edges<<<dim3(36, BB), 256, 0, stream>>>(boxes4, ecount, edges);
  k_nms<<<BB, 256, 0, stream>>>(top_s, ecount, edges, out);
}

// Round 3
// 293.848 us; speedup vs baseline: 1.7557x; 1.0102x over previous
//
#include <hip/hip_runtime.h>
#include <math.h>

#define BB 16
#define TOPK 2000
#define KEEPK 750
#define CAND_CAP 4096
#define EDGE_CAP 8192
#define HIST_BINS 256
#define BIN_BASE 0x3E99u   // (bits of 0.3f) >> 16

// ---------------- ws layout ----------------
#define OFF_HIST   0                       // 16*256*4 = 16384
#define OFF_CCOUNT 16384                   // 64
#define OFF_ECOUNT 16448                   // 64
#define ZERO_BYTES 16512
#define OFF_SBITS  16512                   // B*N*4

// ---------------- kernel 1: scores + histogram (16 elems/thread) ----------------
__global__ __launch_bounds__(256) void k_scores(const float* __restrict__ conf,
                                                const float* __restrict__ iou,
                                                unsigned* __restrict__ sbits,
                                                unsigned* __restrict__ hist, int N) {
  __shared__ unsigned h[HIST_BINS];
  int b = blockIdx.y;
  for (int i = threadIdx.x; i < HIST_BINS; i += blockDim.x) h[i] = 0;
  __syncthreads();
  const float2* c2 = (const float2*)conf + (size_t)b * N;
  const float* iu = iou + (size_t)b * N;
  unsigned* sb = sbits + (size_t)b * N;
  int n0 = blockIdx.x * 4096;
#pragma unroll 4
  for (int k = 0; k < 16; ++k) {
    int n = n0 + k * 256 + threadIdx.x;
    if (n < N) {
      float2 c = c2[n];
      float m = fmaxf(c.x, c.y);
      // correctly-rounded f32 exp via double to match the reference softmax
      float e0 = (float)exp((double)(c.x - m));
      float e1 = (float)exp((double)(c.y - m));
      float p1 = e1 / (e0 + e1);
      float ic = fminf(fmaxf(iu[n], 0.0f), 1.0f);
      float s = sqrtf(p1 * ic);
      s = (s >= 0.3f) ? s : 0.0f;
      unsigned bits = __float_as_uint(s);
      sb[n] = bits;
      if (bits != 0u) {
        int bin = (int)(bits >> 16) - (int)BIN_BASE;
        bin = bin < 0 ? 0 : (bin > 255 ? 255 : bin);
        atomicAdd(&h[bin], 1u);
      }
    }
  }
  __syncthreads();
  for (int i = threadIdx.x; i < HIST_BINS; i += blockDim.x)
    if (h[i]) atomicAdd(&hist[b * HIST_BINS + i], h[i]);
}

// ---------------- kernel 2: fused threshold + compact (1 atomic per block) -------
__global__ __launch_bounds__(256) void k_compact(const unsigned* __restrict__ sbits,
                                                 const unsigned* __restrict__ hist,
                                                 unsigned* __restrict__ ccount,
                                                 unsigned long long* __restrict__ ckeys,
                                                 int N) {
  __shared__ unsigned sT;
  __shared__ unsigned long long masks[32];   // [iter*4 + wave]
  __shared__ unsigned wioff[32];
  __shared__ unsigned blockbase;
  int b = blockIdx.y;
  int tid = threadIdx.x, lane = tid & 63, wv = tid >> 6;

  if (tid < 64) {
    const unsigned* h = hist + b * HIST_BINS;
    unsigned v0 = h[255 - (4 * lane + 0)];
    unsigned v1 = h[255 - (4 * lane + 1)];
    unsigned v2 = h[255 - (4 * lane + 2)];
    unsigned v3 = h[255 - (4 * lane + 3)];
    unsigned p0 = v0, p1 = p0 + v1, p2 = p1 + v2, p3 = p2 + v3;
    unsigned tot = p3, pre = tot;
    for (int off = 1; off < 64; off <<= 1) {
      unsigned q = __shfl_up(pre, off);
      if (lane >= off) pre += q;
    }
    unsigned excl = pre - tot;
    int kk = -1;
    if (excl + p0 >= TOPK) kk = 0;
    else if (excl + p1 >= TOPK) kk = 1;
    else if (excl + p2 >= TOPK) kk = 2;
    else if (excl + p3 >= TOPK) kk = 3;
    unsigned long long m = __ballot(kk >= 0);
    int bin = 0;
    if (m != 0ull) {
      int fl = __ffsll((unsigned long long)m) - 1;
      int fk = __shfl(kk, fl);
      bin = 255 - (4 * fl + fk);
    }
    if (lane == 0) sT = ((unsigned)(BIN_BASE + (unsigned)bin)) << 16;
  }
  __syncthreads();
  unsigned T = sT;

  const unsigned* sb = sbits + (size_t)b * N;
  int n0 = blockIdx.x * 2048;
  unsigned v[8];
  unsigned long long mk[8];
#pragma unroll
  for (int k = 0; k < 8; ++k) {
    int n = n0 + k * 256 + tid;
    v[k] = (n < N) ? sb[n] : 0u;
    bool p = v[k] >= T;
    mk[k] = __ballot(p);
    if (lane == 0) masks[k * 4 + wv] = mk[k];
  }
  __syncthreads();
  if (tid < 64) {
    unsigned c = (tid < 32) ? (unsigned)__popcll(masks[tid]) : 0u;
    unsigned pre = c;
    for (int off = 1; off < 64; off <<= 1) {
      unsigned q = __shfl_up(pre, off);
      if (lane >= off) pre += q;
    }
    if (tid < 32) wioff[tid] = pre - c;
    if (tid == 31) blockbase = atomicAdd(&ccount[b], pre);
  }
  __syncthreads();
  unsigned base = blockbase;
#pragma unroll
  for (int k = 0; k < 8; ++k) {
    if ((mk[k] >> lane) & 1ull) {
      unsigned pos = base + wioff[k * 4 + wv] +
                     (unsigned)__popcll(mk[k] & ((1ull << lane) - 1ull));
      if (pos < CAND_CAP) {
        int n = n0 + k * 256 + tid;
        ckeys[(size_t)b * CAND_CAP + pos] =
            ((unsigned long long)v[k] << 32) | (unsigned)(~(unsigned)n);
      }
    }
  }
}

// ---- kernel 3: hybrid bitonic sort (desc, 4 keys/thread in regs) + decode ----
__global__ __launch_bounds__(1024) void k_sort_decode(
    const unsigned* __restrict__ ccount, const unsigned long long* __restrict__ ckeys,
    const float* __restrict__ loc, float* __restrict__ top_s,
    float* __restrict__ out, float4* __restrict__ boxes4, int N) {
  __shared__ unsigned long long s[CAND_CAP];   // 32 KB
  int b = blockIdx.x;
  int t = threadIdx.x;
  unsigned c = ccount[b];
  if (c > CAND_CAP) c = CAND_CAP;
  const unsigned long long* src = ckeys + (size_t)b * CAND_CAP;
  unsigned long long key[4];
#pragma unroll
  for (int e = 0; e < 4; ++e) {
    int i = 4 * t + e;
    key[e] = (i < (int)c) ? src[i] : 0ull;
  }
  // bitonic network over 4096, overall descending; dir=((i&k)==0) -> lower idx keeps max
  for (int k = 2; k <= CAND_CAP; k <<= 1) {
    for (int j = k >> 1; j > 0; j >>= 1) {
      if (j >= 256) {
        // cross-wave: via LDS
        __syncthreads();
#pragma unroll
        for (int e = 0; e < 4; ++e) s[4 * t + e] = key[e];
        __syncthreads();
        int pbase = (4 * t) ^ j;
        bool own_lo = ((4 * t) & j) == 0;
        bool dir = ((4 * t) & k) == 0;
        bool keep_max = (own_lo == dir);
#pragma unroll
        for (int e = 0; e < 4; ++e) {
          unsigned long long o = s[pbase + e];
          unsigned long long mx = key[e] > o ? key[e] : o;
          unsigned long long mn = key[e] > o ? o : key[e];
          key[e] = keep_max ? mx : mn;
        }
      } else if (j >= 4) {
        // intra-wave: via shuffle
        int d = j >> 2;
        bool own_lo = (t & d) == 0;
        bool dir = ((4 * t) & k) == 0;   // k >= 8 here, so same for all 4 elems
        bool keep_max = (own_lo == dir);
#pragma unroll
        for (int e = 0; e < 4; ++e) {
          unsigned long long o = __shfl_xor(key[e], d, 64);
          unsigned long long mx = key[e] > o ? key[e] : o;
          unsigned long long mn = key[e] > o ? o : key[e];
          key[e] = keep_max ? mx : mn;
        }
      } else {
        // in-register: j == 1 or 2
#pragma unroll
        for (int e = 0; e < 4; ++e) {
          int p = e ^ j;
          if (p > e) {
            int i = 4 * t + e;
            bool dir = ((i & k) == 0);
            bool need = dir ? (key[e] < key[p]) : (key[e] > key[p]);
            if (need) { unsigned long long tmp = key[e]; key[e] = key[p]; key[p] = tmp; }
          }
        }
      }
    }
  }
  // epilogue: threads 0..499 hold ranks 4t..4t+3 -> emit score + decoded box
  if (t < TOPK / 4) {
#pragma unroll
    for (int e = 0; e < 4; ++e) {
      int r = 4 * t + e;
      unsigned long long kk = key[e];
      float sv = __uint_as_float((unsigned)(kk >> 32));
      top_s[b * TOPK + r] = sv;
      unsigned idxu = ~(unsigned)kk;
      if (idxu >= (unsigned)N) idxu = 0;  // pad safety
      int i = (int)idxu;
      int off, fw, st, nm, lvl;
      if (i < 97200)       { lvl = 0; off = 0;      fw = 240; st = 8;  nm = 3; }
      else if (i < 113520) { lvl = 1; off = 97200;  fw = 120; st = 16; nm = 2; }
      else if (i < 117600) { lvl = 2; off = 113520; fw = 60;  st = 32; nm = 2; }
      else                 { lvl = 3; off = 117600; fw = 30;  st = 64; nm = 3; }
      int tt = i - off;
      int cell = tt / nm;
      int kms = tt - cell * nm;
      int row = cell / fw;
      int col = cell - row * fw;
      int msv = (lvl == 0) ? (kms == 0 ? 10 : (kms == 1 ? 16 : 24))
              : (lvl == 1) ? (kms == 0 ? 32 : 48)
              : (lvl == 2) ? (kms == 0 ? 64 : 96)
                           : (kms == 0 ? 128 : (kms == 1 ? 192 : 256));
      float cx  = (float)(((double)col + 0.5) * (double)st / 1920.0);
      float cy  = (float)(((double)row + 0.5) * (double)st / 1080.0);
      float skx = (float)((double)msv / 1920.0);
      float sky = (float)((double)msv / 1080.0);
      const float2* lp2 = (const float2*)(loc + ((size_t)b * N + (size_t)i) * 14);
      float l[14];
#pragma unroll
      for (int q = 0; q < 7; ++q) { float2 v = lp2[q]; l[2 * q] = v.x; l[2 * q + 1] = v.y; }
      float cx2 = cx + (l[0] * 0.1f) * skx;
      float cy2 = cy + (l[1] * 0.1f) * sky;
      float wx = skx * expf(l[2] * 0.1f);
      float wy = sky * expf(l[3] * 0.2f);
      float x1 = cx2 - wx * 0.5f, y1 = cy2 - wy * 0.5f;
      float x2 = x1 + wx, y2 = y1 + wy;
      float X1 = x1 * 1920.0f, Y1 = y1 * 1080.0f, X2 = x2 * 1920.0f, Y2 = y2 * 1080.0f;
      float* o = out + ((size_t)b * TOPK + r) * 15;
      o[0] = X1; o[1] = Y1; o[2] = X2; o[3] = Y2;
#pragma unroll
      for (int q = 0; q < 5; ++q) {
        o[4 + 2 * q] = (cx + (l[4 + 2 * q] * 0.1f) * skx) * 1920.0f;
        o[5 + 2 * q] = (cy + (l[5 + 2 * q] * 0.1f) * sky) * 1080.0f;
      }
      boxes4[b * TOPK + r] = make_float4(X1, Y1, X2, Y2);
    }
  }
}

// ---- kernel 4: sparse overlap edges, 256x256 triangular tiles, 1 atomic/block ----
__global__ __launch_bounds__(256) void k_edges(const float4* __restrict__ boxes4,
                                               unsigned* __restrict__ ecount,
                                               unsigned* __restrict__ edges) {
  __shared__ float4 cb[256];
  __shared__ unsigned loc_e[1024];
  __shared__ unsigned lcnt, gbase;
  int b = blockIdx.y;
  int t = blockIdx.x;                 // 0..35 triangular tile id
  int ib = 0;
  while ((ib + 1) * (ib + 2) / 2 <= t) ++ib;
  int jb = t - ib * (ib + 1) / 2;
  int tid = threadIdx.x;
  if (tid == 0) lcnt = 0;
  int j0 = jb * 256;
  {
    int j = j0 + tid;
    cb[tid] = (j < TOPK) ? boxes4[b * TOPK + j]
                         : make_float4(-1e30f, -1e30f, -1e30f, -1e30f);
  }
  __syncthreads();
  int r = ib * 256 + tid;
  bool valid = r < TOPK;
  float4 A = valid ? boxes4[b * TOPK + r] : make_float4(0, 0, 0, 0);
  float areaA = fmaxf(A.z - A.x, 0.f) * fmaxf(A.w - A.y, 0.f);
  int cmax = r - j0;
  if (cmax > 256) cmax = 256;
  if (!valid) cmax = 0;
  for (int c = 0; c < cmax; ++c) {
    float4 Bx = cb[c];
    float xx1 = fmaxf(A.x, Bx.x), yy1 = fmaxf(A.y, Bx.y);
    float xx2 = fminf(A.z, Bx.z), yy2 = fminf(A.w, Bx.w);
    float w = fmaxf(xx2 - xx1, 0.f), hgt = fmaxf(yy2 - yy1, 0.f);
    float inter = w * hgt;
    float areaB = fmaxf(Bx.z - Bx.x, 0.f) * fmaxf(Bx.w - Bx.y, 0.f);
    float iouv = inter / (areaA + areaB - inter + 1e-9f);
    if (iouv > 0.3f) {
      unsigned p = atomicAdd(&lcnt, 1u);
      if (p < 1024u) loc_e[p] = ((unsigned)r << 16) | (unsigned)(j0 + c);
    }
  }
  __syncthreads();
  unsigned cnt = lcnt;
  if (cnt > 1024u) cnt = 1024u;
  if (tid == 0 && cnt) gbase = atomicAdd(&ecount[b], cnt);
  __syncthreads();
  if (cnt)
    for (unsigned e = tid; e < cnt; e += 256) {
      unsigned p = gbase + e;
      if (p < EDGE_CAP) edges[b * EDGE_CAP + p] = loc_e[e];
    }
}

// ---- kernel 5: greedy NMS (Jacobi fixpoint, LDS edge cache, early exit) ----
__global__ __launch_bounds__(256) void k_nms(const float* __restrict__ top_s,
                                             const unsigned* __restrict__ ecount,
                                             const unsigned* __restrict__ edges,
                                             float* __restrict__ out) {
  int b = blockIdx.x;
  __shared__ unsigned long long A[32], K[32], S[32];
  __shared__ unsigned pref[32];
  __shared__ unsigned ecache[2048];
  __shared__ int changed;
  int tid = threadIdx.x, lane = tid & 63, wv = tid >> 6;
  for (int base = 0; base < 2048; base += 256) {
    int i = base + tid;
    bool act = (i < TOPK) && (top_s[b * TOPK + i] > 0.0f);
    unsigned long long m = __ballot(act);
    if (lane == 0) { int w = (base >> 6) + wv; A[w] = m; K[w] = m; }
  }
  unsigned E = ecount[b];
  if (E > EDGE_CAP) E = EDGE_CAP;
  unsigned Ec = E > 2048u ? 2048u : E;
  for (unsigned e = tid; e < Ec; e += 256) ecache[e] = edges[b * EDGE_CAP + e];
  __syncthreads();
  for (int it = 0; it < 32; ++it) {
    if (tid == 0) changed = 0;
    if (tid < 32) S[tid] = 0ull;
    __syncthreads();
    for (unsigned e = tid; e < Ec; e += 256) {
      unsigned v = ecache[e];
      unsigned i = v >> 16, j = v & 0xFFFFu;
      if ((K[j >> 6] >> (j & 63)) & 1ull) atomicOr(&S[i >> 6], 1ull << (i & 63));
    }
    for (unsigned e = 2048u + tid; e < E; e += 256) {
      unsigned v = edges[b * EDGE_CAP + e];
      unsigned i = v >> 16, j = v & 0xFFFFu;
      if ((K[j >> 6] >> (j & 63)) & 1ull) atomicOr(&S[i >> 6], 1ull << (i & 63));
    }
    __syncthreads();
    if (tid < 32) {
      unsigned long long nk = A[tid] & ~S[tid];
      if (nk != K[tid]) { K[tid] = nk; changed = 1; }
    }
    __syncthreads();
    if (!changed) break;
  }
  if (tid == 0) {
    unsigned acc = 0;
    for (int w = 0; w < 32; ++w) { pref[w] = acc; acc += (unsigned)__popcll(K[w]); }
  }
  __syncthreads();
  for (int base = 0; base < 2048; base += 256) {
    int i = base + tid;
    if (i < TOPK) {
      int w = i >> 6;
      unsigned long long bit = (K[w] >> (i & 63)) & 1ull;
      unsigned rank = pref[w] + (unsigned)__popcll(K[w] & ((1ull << (i & 63)) - 1ull)) +
                      (unsigned)bit;
      float sv = top_s[b * TOPK + i];
      out[((size_t)b * TOPK + i) * 15 + 14] = (bit && rank <= KEEPK) ? sv : 0.0f;
    }
  }
}

extern "C" void kernel_launch(void* const* d_in, const int* in_sizes, int n_in,
                              void* d_out, int out_size, void* d_ws, size_t ws_size,
                              hipStream_t stream) {
  const float* loc  = (const float*)d_in[0];
  const float* conf = (const float*)d_in[1];
  const float* iou  = (const float*)d_in[2];
  float* out = (float*)d_out;
  int N = in_sizes[2] / BB;  // iou is [B,N,1]

  char* ws = (char*)d_ws;
  unsigned* hist   = (unsigned*)(ws + OFF_HIST);
  unsigned* ccount = (unsigned*)(ws + OFF_CCOUNT);
  unsigned* ecount = (unsigned*)(ws + OFF_ECOUNT);
  unsigned* sbits  = (unsigned*)(ws + OFF_SBITS);
  size_t off = (size_t)OFF_SBITS + (size_t)BB * N * 4;
  off = (off + 15) & ~(size_t)15;
  unsigned long long* ckeys = (unsigned long long*)(ws + off); off += (size_t)BB * CAND_CAP * 8;
  float* top_s = (float*)(ws + off);       off += (size_t)BB * TOPK * 4;
  off = (off + 15) & ~(size_t)15;
  float4* boxes4 = (float4*)(ws + off);    off += (size_t)BB * TOPK * 16;
  unsigned* edges = (unsigned*)(ws + off); off += (size_t)BB * EDGE_CAP * 4;

  hipMemsetAsync(ws, 0, ZERO_BYTES, stream);

  k_scores<<<dim3((N + 4095) / 4096, BB), 256, 0, stream>>>(conf, iou, sbits, hist, N);
  k_compact<<<dim3((N + 2047) / 2048, BB), 256, 0, stream>>>(sbits, hist, ccount, ckeys, N);
  k_sort_decode<<<BB, 1024, 0, stream>>>(ccount, ckeys, loc, top_s, out, boxes4, N);
  k_edges<<<dim3(36, BB), 256, 0, stream>>>(boxes4, ecount, edges);
  k_nms<<<BB, 256, 0, stream>>>(top_s, ecount, edges, out);
}